// Round 1
// baseline (44.993 us; speedup 1.0000x reference)
//
#include <hip/hip_runtime.h>
#include <math.h>

#define T_TOK 1024   // B*S = 2*512
#define D 512        // D_IN = D_OUT = 512
#define EPS 1e-5f

// ---------------------------------------------------------------------------
// Kernel 1: P[z][t][e] = sum_d X[t][d] * Wz[e][d]   (z=0:W_in, 1:W_out, 2:W_b)
// Classic fp32 tiled GEMM, C = A * B^T with both operands K-contiguous.
// BM=BN=64, BK=32, 256 threads, 4x4 micro-tile per thread.
// LDS tiles stored transposed [k][m] with +4 pad so inner-loop reads are
// 16B-aligned float4 (stride 68 floats = 272B, 272%16==0).
// ---------------------------------------------------------------------------
template<int BM, int BN, int BK>
__global__ __launch_bounds__(256) void gemm3_kernel(
    const float* __restrict__ X,
    const float* __restrict__ W0,
    const float* __restrict__ W1,
    const float* __restrict__ W2,
    float* __restrict__ P)
{
    __shared__ float As[BK][BM + 4];
    __shared__ float Bs[BK][BN + 4];

    const int tid = threadIdx.x;
    const int tx = tid & 15;          // n direction
    const int ty = tid >> 4;          // m direction
    const int bm = blockIdx.x * BM;
    const int bn = blockIdx.y * BN;
    const int z  = blockIdx.z;
    const float* __restrict__ W = (z == 0) ? W0 : (z == 1) ? W1 : W2;

    float acc[4][4];
    #pragma unroll
    for (int i = 0; i < 4; ++i)
        #pragma unroll
        for (int j = 0; j < 4; ++j) acc[i][j] = 0.f;

    constexpr int K4   = BK / 4;               // float4s per row of a tile
    constexpr int A_IT = (BM * BK) / (256 * 4);
    constexpr int B_IT = (BN * BK) / (256 * 4);

    for (int k0 = 0; k0 < D; k0 += BK) {
        #pragma unroll
        for (int i = 0; i < A_IT; ++i) {
            int idx = tid + i * 256;           // float4 index within tile
            int row = idx / K4;
            int c4  = (idx % K4) * 4;
            float4 v = *reinterpret_cast<const float4*>(
                X + (size_t)(bm + row) * D + k0 + c4);
            As[c4 + 0][row] = v.x; As[c4 + 1][row] = v.y;
            As[c4 + 2][row] = v.z; As[c4 + 3][row] = v.w;
        }
        #pragma unroll
        for (int i = 0; i < B_IT; ++i) {
            int idx = tid + i * 256;
            int row = idx / K4;
            int c4  = (idx % K4) * 4;
            float4 v = *reinterpret_cast<const float4*>(
                W + (size_t)(bn + row) * D + k0 + c4);
            Bs[c4 + 0][row] = v.x; Bs[c4 + 1][row] = v.y;
            Bs[c4 + 2][row] = v.z; Bs[c4 + 3][row] = v.w;
        }
        __syncthreads();

        #pragma unroll
        for (int k = 0; k < BK; ++k) {
            float4 a = *reinterpret_cast<const float4*>(&As[k][ty * 4]);
            float4 b = *reinterpret_cast<const float4*>(&Bs[k][tx * 4]);
            float av[4] = {a.x, a.y, a.z, a.w};
            float bv[4] = {b.x, b.y, b.z, b.w};
            #pragma unroll
            for (int i = 0; i < 4; ++i)
                #pragma unroll
                for (int j = 0; j < 4; ++j)
                    acc[i][j] = fmaf(av[i], bv[j], acc[i][j]);
        }
        __syncthreads();
    }

    float* __restrict__ Pz = P + (size_t)z * T_TOK * D;
    #pragma unroll
    for (int i = 0; i < 4; ++i) {
        const int row = bm + ty * 4 + i;
        #pragma unroll
        for (int j = 0; j < 4; ++j) {
            Pz[(size_t)row * D + bn + tx * 4 + j] = acc[i][j];
        }
    }
}

// ---------------------------------------------------------------------------
// Kernel 2: per-token epilogue using the rank-1 layernorm collapse.
//   mu1 = mean(w1), var1 = var(w1), S = <w1,x> - mu1*sum(x)
//   y[i] = w2[i]*S*rsqrt(w2[i]^2*var1 + eps) + (wb[i]-mu_b)*rsqrt(var_b+eps)
// One block (256 threads) per token.
// ---------------------------------------------------------------------------
__global__ __launch_bounds__(256) void epilogue_kernel(
    const float* __restrict__ X,
    const float* __restrict__ P,    // [3][T_TOK][D]
    float* __restrict__ Y)
{
    const int t   = blockIdx.x;
    const int tid = threadIdx.x;

    const float* __restrict__ w1 = P + (size_t)t * D;
    const float* __restrict__ w2 = P + (size_t)T_TOK * D     + (size_t)t * D;
    const float* __restrict__ wb = P + (size_t)T_TOK * D * 2 + (size_t)t * D;
    const float* __restrict__ x  = X + (size_t)t * D;

    float sx = 0.f, s1 = 0.f, q1 = 0.f, d1x = 0.f, sb = 0.f, qb = 0.f;
    #pragma unroll
    for (int i = tid; i < D; i += 256) {
        float xv  = x[i];
        float w1v = w1[i];
        float wbv = wb[i];
        sx  += xv;
        s1  += w1v;
        q1  += w1v * w1v;
        d1x += w1v * xv;
        sb  += wbv;
        qb  += wbv * wbv;
    }

    // wave64 shuffle reduction
    #pragma unroll
    for (int off = 32; off > 0; off >>= 1) {
        sx  += __shfl_down(sx,  off);
        s1  += __shfl_down(s1,  off);
        q1  += __shfl_down(q1,  off);
        d1x += __shfl_down(d1x, off);
        sb  += __shfl_down(sb,  off);
        qb  += __shfl_down(qb,  off);
    }

    __shared__ float red[6][4];
    const int wave = tid >> 6;
    if ((tid & 63) == 0) {
        red[0][wave] = sx;  red[1][wave] = s1;  red[2][wave] = q1;
        red[3][wave] = d1x; red[4][wave] = sb;  red[5][wave] = qb;
    }
    __syncthreads();
    sx  = red[0][0] + red[0][1] + red[0][2] + red[0][3];
    s1  = red[1][0] + red[1][1] + red[1][2] + red[1][3];
    q1  = red[2][0] + red[2][1] + red[2][2] + red[2][3];
    d1x = red[3][0] + red[3][1] + red[3][2] + red[3][3];
    sb  = red[4][0] + red[4][1] + red[4][2] + red[4][3];
    qb  = red[5][0] + red[5][1] + red[5][2] + red[5][3];

    const float inv_d = 1.f / (float)D;
    const float mu1   = s1 * inv_d;
    const float var1  = q1 * inv_d - mu1 * mu1;
    const float Sv    = d1x - mu1 * sx;
    const float mub   = sb * inv_d;
    const float varb  = qb * inv_d - mub * mub;
    const float rb    = rsqrtf(varb + EPS);

    #pragma unroll
    for (int i = tid; i < D; i += 256) {
        float w2v = w2[i];
        float wbv = wb[i];
        float y = w2v * Sv * rsqrtf(w2v * w2v * var1 + EPS)
                + (wbv - mub) * rb;
        Y[(size_t)t * D + i] = y;
    }
}

extern "C" void kernel_launch(void* const* d_in, const int* in_sizes, int n_in,
                              void* d_out, int out_size, void* d_ws, size_t ws_size,
                              hipStream_t stream) {
    const float* x     = (const float*)d_in[0];
    const float* W_in  = (const float*)d_in[1];
    const float* W_out = (const float*)d_in[2];
    const float* W_b   = (const float*)d_in[3];
    float* Y = (float*)d_out;
    float* P = (float*)d_ws;   // needs 3*1024*512*4 = 6 MB

    constexpr int BM = 64, BN = 64, BK = 32;
    dim3 grid1(T_TOK / BM, D / BN, 3);
    gemm3_kernel<BM, BN, BK><<<grid1, 256, 0, stream>>>(x, W_in, W_out, W_b, P);

    epilogue_kernel<<<dim3(T_TOK), 256, 0, stream>>>(x, P, Y);
}

// Round 4
// 34.868 us; speedup vs baseline: 1.2904x; 1.2904x over previous
//
#include <hip/hip_runtime.h>
#include <math.h>

#define T_TOK 1024   // B*S
#define D 512        // D_IN = D_OUT
#define EPS 1e-5f

typedef short bf16x8 __attribute__((ext_vector_type(8)));
typedef float f32x4  __attribute__((ext_vector_type(4)));

__device__ __forceinline__ unsigned short f2bf(float f) {
    unsigned int u = __builtin_bit_cast(unsigned int, f);
    u += 0x7FFFu + ((u >> 16) & 1u);   // RNE
    return (unsigned short)(u >> 16);
}
__device__ __forceinline__ float bf2f(unsigned short h) {
    return __builtin_bit_cast(float, (unsigned int)h << 16);
}

// ---------------------------------------------------------------------------
// Kernel 1: P[z][t][e] = sum_d X[t][d] * Wz[e][d], bf16 MFMA.
// BM=BN=64, BK=64, 4 waves (2x2), wave owns 32x32 (2x2 16x16 fragments).
//
// z==1 (W_out -> w2) uses SPLIT-PRECISION bf16: v = hi + lo (lo exact fp32
// residual), acc = Xh*Wh + Xh*Wl + Xl*Wh. Needed because the epilogue's
// w2 / sqrt(w2^2 var1 + eps) is a step of width sqrt(eps/var1)~0.0055
// around w2=0, narrower than plain-bf16 GEMM absolute error (~0.008).
// z==0,2 (w1, wb) have only relative sensitivity -> plain bf16.
//
// C-write is self-calibrating via two probe MFMAs (correct under any
// self-consistent HW fragment layout).
// ---------------------------------------------------------------------------
#define BK 64
#define LSTR 72   // bf16 elems per LDS row (64 + 8 pad)

__global__ __launch_bounds__(256) void gemm3_mfma(
    const float* __restrict__ X,
    const float* __restrict__ W0,
    const float* __restrict__ W1,
    const float* __restrict__ W2,
    float* __restrict__ P)
{
    __shared__ __align__(16) unsigned short As [64 * LSTR];
    __shared__ __align__(16) unsigned short Bs [64 * LSTR];
    __shared__ __align__(16) unsigned short Asl[64 * LSTR];
    __shared__ __align__(16) unsigned short Bsl[64 * LSTR];

    const int tid  = threadIdx.x;
    const int lane = tid & 63;
    const int wid  = tid >> 6;
    const int wr   = wid >> 1;
    const int wc   = wid & 1;
    const int bm   = blockIdx.x * 64;
    const int bn   = blockIdx.y * 64;
    const int z    = blockIdx.z;
    const bool split = (z == 1);
    const float* __restrict__ W = (z == 0) ? W0 : (z == 1) ? W1 : W2;

    const int l15 = lane & 15;
    const int l4  = lane >> 4;

    // --- layout probes: D1[m][n]=m, D2[m][n]=n under the load convention ---
    bf16x8 aP1 = {}, bP1 = {}, aP2 = {}, bP2 = {};
    if (l4 == 0) {
        aP1[0] = (short)f2bf((float)l15);
        bP1[0] = (short)f2bf(1.0f);
        aP2[0] = (short)f2bf(1.0f);
        bP2[0] = (short)f2bf((float)l15);
    }
    f32x4 zero = {};
    f32x4 D1 = __builtin_amdgcn_mfma_f32_16x16x32_bf16(aP1, bP1, zero, 0, 0, 0);
    f32x4 D2 = __builtin_amdgcn_mfma_f32_16x16x32_bf16(aP2, bP2, zero, 0, 0, 0);
    int mi[4], ni[4];
    #pragma unroll
    for (int r = 0; r < 4; ++r) { mi[r] = (int)D1[r]; ni[r] = (int)D2[r]; }

    f32x4 acc[2][2] = {};

    for (int k0 = 0; k0 < D; k0 += BK) {
        #pragma unroll
        for (int i = 0; i < 4; ++i) {
            int f   = tid + i * 256;
            int row = f >> 4;
            int kc4 = (f & 15) * 4;
            float4 v = *reinterpret_cast<const float4*>(
                X + (size_t)(bm + row) * D + k0 + kc4);
            unsigned short h0 = f2bf(v.x), h1 = f2bf(v.y),
                           h2 = f2bf(v.z), h3 = f2bf(v.w);
            unsigned short* p = &As[row * LSTR + kc4];
            p[0] = h0; p[1] = h1; p[2] = h2; p[3] = h3;
            if (split) {
                unsigned short* q = &Asl[row * LSTR + kc4];
                q[0] = f2bf(v.x - bf2f(h0));
                q[1] = f2bf(v.y - bf2f(h1));
                q[2] = f2bf(v.z - bf2f(h2));
                q[3] = f2bf(v.w - bf2f(h3));
            }
        }
        #pragma unroll
        for (int i = 0; i < 4; ++i) {
            int f   = tid + i * 256;
            int row = f >> 4;
            int kc4 = (f & 15) * 4;
            float4 v = *reinterpret_cast<const float4*>(
                W + (size_t)(bn + row) * D + k0 + kc4);
            unsigned short h0 = f2bf(v.x), h1 = f2bf(v.y),
                           h2 = f2bf(v.z), h3 = f2bf(v.w);
            unsigned short* p = &Bs[row * LSTR + kc4];
            p[0] = h0; p[1] = h1; p[2] = h2; p[3] = h3;
            if (split) {
                unsigned short* q = &Bsl[row * LSTR + kc4];
                q[0] = f2bf(v.x - bf2f(h0));
                q[1] = f2bf(v.y - bf2f(h1));
                q[2] = f2bf(v.z - bf2f(h2));
                q[3] = f2bf(v.w - bf2f(h3));
            }
        }
        __syncthreads();

        #pragma unroll
        for (int kc = 0; kc < 2; ++kc) {
            bf16x8 a[2], b[2];
            #pragma unroll
            for (int fm = 0; fm < 2; ++fm) {
                int row = wr * 32 + fm * 16 + l15;
                a[fm] = *reinterpret_cast<const bf16x8*>(
                    &As[row * LSTR + kc * 32 + l4 * 8]);
            }
            #pragma unroll
            for (int fn = 0; fn < 2; ++fn) {
                int row = wc * 32 + fn * 16 + l15;
                b[fn] = *reinterpret_cast<const bf16x8*>(
                    &Bs[row * LSTR + kc * 32 + l4 * 8]);
            }
            #pragma unroll
            for (int fm = 0; fm < 2; ++fm)
                #pragma unroll
                for (int fn = 0; fn < 2; ++fn)
                    acc[fm][fn] = __builtin_amdgcn_mfma_f32_16x16x32_bf16(
                        a[fm], b[fn], acc[fm][fn], 0, 0, 0);

            if (split) {
                bf16x8 al[2], bl[2];
                #pragma unroll
                for (int fm = 0; fm < 2; ++fm) {
                    int row = wr * 32 + fm * 16 + l15;
                    al[fm] = *reinterpret_cast<const bf16x8*>(
                        &Asl[row * LSTR + kc * 32 + l4 * 8]);
                }
                #pragma unroll
                for (int fn = 0; fn < 2; ++fn) {
                    int row = wc * 32 + fn * 16 + l15;
                    bl[fn] = *reinterpret_cast<const bf16x8*>(
                        &Bsl[row * LSTR + kc * 32 + l4 * 8]);
                }
                #pragma unroll
                for (int fm = 0; fm < 2; ++fm)
                    #pragma unroll
                    for (int fn = 0; fn < 2; ++fn) {
                        acc[fm][fn] = __builtin_amdgcn_mfma_f32_16x16x32_bf16(
                            a[fm], bl[fn], acc[fm][fn], 0, 0, 0);
                        acc[fm][fn] = __builtin_amdgcn_mfma_f32_16x16x32_bf16(
                            al[fm], b[fn], acc[fm][fn], 0, 0, 0);
                    }
            }
        }
        __syncthreads();
    }

    float* __restrict__ Pz = P + (size_t)z * T_TOK * D;
    #pragma unroll
    for (int fm = 0; fm < 2; ++fm)
        #pragma unroll
        for (int fn = 0; fn < 2; ++fn)
            #pragma unroll
            for (int r = 0; r < 4; ++r) {
                int row = bm + wr * 32 + fm * 16 + mi[r];
                int col = bn + wc * 32 + fn * 16 + ni[r];
                Pz[(size_t)row * D + col] = acc[fm][fn][r];
            }
}

// ---------------------------------------------------------------------------
// Kernel 2: per-token epilogue via rank-1 layernorm collapse.
// ---------------------------------------------------------------------------
__global__ __launch_bounds__(256) void epilogue_kernel(
    const float* __restrict__ X,
    const float* __restrict__ P,    // [3][T_TOK][D]
    float* __restrict__ Y)
{
    const int t   = blockIdx.x;
    const int tid = threadIdx.x;

    const float* __restrict__ w1 = P + (size_t)t * D;
    const float* __restrict__ w2 = P + (size_t)T_TOK * D     + (size_t)t * D;
    const float* __restrict__ wb = P + (size_t)T_TOK * D * 2 + (size_t)t * D;
    const float* __restrict__ x  = X + (size_t)t * D;

    float sx = 0.f, s1 = 0.f, q1 = 0.f, d1x = 0.f, sb = 0.f, qb = 0.f;
    #pragma unroll
    for (int i = tid; i < D; i += 256) {
        float xv  = x[i];
        float w1v = w1[i];
        float wbv = wb[i];
        sx  += xv;
        s1  += w1v;
        q1  += w1v * w1v;
        d1x += w1v * xv;
        sb  += wbv;
        qb  += wbv * wbv;
    }

    #pragma unroll
    for (int off = 32; off > 0; off >>= 1) {
        sx  += __shfl_down(sx,  off);
        s1  += __shfl_down(s1,  off);
        q1  += __shfl_down(q1,  off);
        d1x += __shfl_down(d1x, off);
        sb  += __shfl_down(sb,  off);
        qb  += __shfl_down(qb,  off);
    }

    __shared__ float red[6][4];
    const int wave = tid >> 6;
    if ((tid & 63) == 0) {
        red[0][wave] = sx;  red[1][wave] = s1;  red[2][wave] = q1;
        red[3][wave] = d1x; red[4][wave] = sb;  red[5][wave] = qb;
    }
    __syncthreads();
    sx  = red[0][0] + red[0][1] + red[0][2] + red[0][3];
    s1  = red[1][0] + red[1][1] + red[1][2] + red[1][3];
    q1  = red[2][0] + red[2][1] + red[2][2] + red[2][3];
    d1x = red[3][0] + red[3][1] + red[3][2] + red[3][3];
    sb  = red[4][0] + red[4][1] + red[4][2] + red[4][3];
    qb  = red[5][0] + red[5][1] + red[5][2] + red[5][3];

    const float inv_d = 1.f / (float)D;
    const float mu1   = s1 * inv_d;
    const float var1  = q1 * inv_d - mu1 * mu1;
    const float Sv    = d1x - mu1 * sx;
    const float mub   = sb * inv_d;
    const float varb  = qb * inv_d - mub * mub;
    const float rb    = rsqrtf(varb + EPS);

    #pragma unroll
    for (int i = tid; i < D; i += 256) {
        float w2v = w2[i];
        float wbv = wb[i];
        float y = w2v * Sv * rsqrtf(w2v * w2v * var1 + EPS)
                + (wbv - mub) * rb;
        Y[(size_t)t * D + i] = y;
    }
}

extern "C" void kernel_launch(void* const* d_in, const int* in_sizes, int n_in,
                              void* d_out, int out_size, void* d_ws, size_t ws_size,
                              hipStream_t stream) {
    const float* x     = (const float*)d_in[0];
    const float* W_in  = (const float*)d_in[1];
    const float* W_out = (const float*)d_in[2];
    const float* W_b   = (const float*)d_in[3];
    float* Y = (float*)d_out;
    float* P = (float*)d_ws;   // 3*1024*512*4 = 6 MB

    dim3 grid1(T_TOK / 64, D / 64, 3);
    gemm3_mfma<<<grid1, 256, 0, stream>>>(x, W_in, W_out, W_b, P);

    epilogue_kernel<<<dim3(T_TOK), 256, 0, stream>>>(x, P, Y);
}

// Round 5
// 34.843 us; speedup vs baseline: 1.2913x; 1.0007x over previous
//
#include <hip/hip_runtime.h>
#include <math.h>

#define T_TOK 1024   // B*S
#define D 512        // D_IN = D_OUT
#define EPS 1e-5f

typedef short bf16x8 __attribute__((ext_vector_type(8)));
typedef float f32x4  __attribute__((ext_vector_type(4)));

__device__ __forceinline__ unsigned short f2bf(float f) {
    unsigned int u = __builtin_bit_cast(unsigned int, f);
    u += 0x7FFFu + ((u >> 16) & 1u);   // RNE
    return (unsigned short)(u >> 16);
}
__device__ __forceinline__ float bf2f(unsigned short h) {
    return __builtin_bit_cast(float, (unsigned int)h << 16);
}

// workspace layout (bytes):
//   P    f32 [3][1024][512]  @ 0         (6 MB)
//   Xh   u16 [1024][512]     @ 6291456   (1 MB)
//   Xl   u16 [1024][512]     @ 7340032   (1 MB)
//   Wh   u16 [3][512][512]   @ 8388608   (1.5 MB)
//   W1l  u16 [512][512]      @ 9961472   (0.5 MB)

// ---------------------------------------------------------------------------
// Kernel 0: one-shot fp32 -> bf16 conversion (hi everywhere; exact-residual
// lo for X and W_out, needed by the split-precision w2 GEMM).
// ---------------------------------------------------------------------------
__global__ __launch_bounds__(256) void convert_kernel(
    const float* __restrict__ X,
    const float* __restrict__ W0,
    const float* __restrict__ W1,
    const float* __restrict__ W2,
    unsigned short* __restrict__ Xh,
    unsigned short* __restrict__ Xl,
    unsigned short* __restrict__ Wh,
    unsigned short* __restrict__ W1l)
{
    constexpr int NX4 = T_TOK * D / 4;   // 131072
    constexpr int NW4 = D * D / 4;       // 65536
    const int i = blockIdx.x * 256 + threadIdx.x;

    if (i < NX4) {
        float4 v = reinterpret_cast<const float4*>(X)[i];
        unsigned short h0 = f2bf(v.x), h1 = f2bf(v.y),
                       h2 = f2bf(v.z), h3 = f2bf(v.w);
        ushort4 h = {h0, h1, h2, h3};
        ushort4 l = {f2bf(v.x - bf2f(h0)), f2bf(v.y - bf2f(h1)),
                     f2bf(v.z - bf2f(h2)), f2bf(v.w - bf2f(h3))};
        reinterpret_cast<ushort4*>(Xh)[i] = h;
        reinterpret_cast<ushort4*>(Xl)[i] = l;
    } else {
        int w = i - NX4;                 // 0 .. 3*NW4-1
        int z = w / NW4;
        int j = w - z * NW4;
        const float* Wsrc = (z == 0) ? W0 : (z == 1) ? W1 : W2;
        float4 v = reinterpret_cast<const float4*>(Wsrc)[j];
        unsigned short h0 = f2bf(v.x), h1 = f2bf(v.y),
                       h2 = f2bf(v.z), h3 = f2bf(v.w);
        ushort4 h = {h0, h1, h2, h3};
        reinterpret_cast<ushort4*>(Wh)[w] = h;
        if (z == 1) {
            ushort4 l = {f2bf(v.x - bf2f(h0)), f2bf(v.y - bf2f(h1)),
                         f2bf(v.z - bf2f(h2)), f2bf(v.w - bf2f(h3))};
            reinterpret_cast<ushort4*>(W1l)[j] = l;
        }
    }
}

// ---------------------------------------------------------------------------
// Kernel 1: LDS-free register GEMM. P[z][t][e] = sum_d X[t][d]*Wz[e][d].
// Block = 4 waves (2x2), each wave owns a 32x32 tile (2x2 16x16 frags).
// Fragments load straight from L2-resident bf16 buffers (16B/lane, aligned).
// z==1 accumulates Xh*Wh + Xh*Wl + Xl*Wh (split precision for the w2 cliff).
// C-write is self-calibrating via two probe MFMAs.
// ---------------------------------------------------------------------------
__global__ __launch_bounds__(256) void gemm_reg(
    const unsigned short* __restrict__ Xh,
    const unsigned short* __restrict__ Xl,
    const unsigned short* __restrict__ Wh,
    const unsigned short* __restrict__ W1l,
    float* __restrict__ P)
{
    const int tid  = threadIdx.x;
    const int lane = tid & 63;
    const int wid  = tid >> 6;
    const int wr   = wid >> 1;
    const int wc   = wid & 1;
    const int bm   = blockIdx.x * 64;
    const int bn   = blockIdx.y * 64;
    const int z    = blockIdx.z;
    const int l15  = lane & 15;
    const int l4   = lane >> 4;
    const int koff = l4 * 8;

    const unsigned short* __restrict__ A = Xh;
    const unsigned short* __restrict__ B = Wh + (size_t)z * D * D;

    // --- layout probes: D1[m][n]=m, D2[m][n]=n under the load convention ---
    bf16x8 aP1 = {}, bP1 = {}, aP2 = {}, bP2 = {};
    if (l4 == 0) {
        aP1[0] = (short)f2bf((float)l15);
        bP1[0] = (short)f2bf(1.0f);
        aP2[0] = (short)f2bf(1.0f);
        bP2[0] = (short)f2bf((float)l15);
    }
    f32x4 zero = {};
    f32x4 D1 = __builtin_amdgcn_mfma_f32_16x16x32_bf16(aP1, bP1, zero, 0, 0, 0);
    f32x4 D2 = __builtin_amdgcn_mfma_f32_16x16x32_bf16(aP2, bP2, zero, 0, 0, 0);
    int mi[4], ni[4];
    #pragma unroll
    for (int r = 0; r < 4; ++r) { mi[r] = (int)D1[r]; ni[r] = (int)D2[r]; }

    const size_t ar0 = (size_t)(bm + wr * 32 + l15) * D + koff;
    const size_t ar1 = ar0 + 16 * D;
    const size_t br0 = (size_t)(bn + wc * 32 + l15) * D + koff;
    const size_t br1 = br0 + 16 * D;

    f32x4 acc[2][2] = {};

    if (z != 1) {
        #pragma unroll
        for (int k0 = 0; k0 < D; k0 += 32) {
            bf16x8 a0 = *reinterpret_cast<const bf16x8*>(A + ar0 + k0);
            bf16x8 a1 = *reinterpret_cast<const bf16x8*>(A + ar1 + k0);
            bf16x8 b0 = *reinterpret_cast<const bf16x8*>(B + br0 + k0);
            bf16x8 b1 = *reinterpret_cast<const bf16x8*>(B + br1 + k0);
            acc[0][0] = __builtin_amdgcn_mfma_f32_16x16x32_bf16(a0, b0, acc[0][0], 0, 0, 0);
            acc[0][1] = __builtin_amdgcn_mfma_f32_16x16x32_bf16(a0, b1, acc[0][1], 0, 0, 0);
            acc[1][0] = __builtin_amdgcn_mfma_f32_16x16x32_bf16(a1, b0, acc[1][0], 0, 0, 0);
            acc[1][1] = __builtin_amdgcn_mfma_f32_16x16x32_bf16(a1, b1, acc[1][1], 0, 0, 0);
        }
    } else {
        #pragma unroll
        for (int k0 = 0; k0 < D; k0 += 32) {
            bf16x8 a0  = *reinterpret_cast<const bf16x8*>(A   + ar0 + k0);
            bf16x8 a1  = *reinterpret_cast<const bf16x8*>(A   + ar1 + k0);
            bf16x8 b0  = *reinterpret_cast<const bf16x8*>(B   + br0 + k0);
            bf16x8 b1  = *reinterpret_cast<const bf16x8*>(B   + br1 + k0);
            bf16x8 al0 = *reinterpret_cast<const bf16x8*>(Xl  + ar0 + k0);
            bf16x8 al1 = *reinterpret_cast<const bf16x8*>(Xl  + ar1 + k0);
            bf16x8 bl0 = *reinterpret_cast<const bf16x8*>(W1l + br0 + k0);
            bf16x8 bl1 = *reinterpret_cast<const bf16x8*>(W1l + br1 + k0);
            acc[0][0] = __builtin_amdgcn_mfma_f32_16x16x32_bf16(a0, b0, acc[0][0], 0, 0, 0);
            acc[0][1] = __builtin_amdgcn_mfma_f32_16x16x32_bf16(a0, b1, acc[0][1], 0, 0, 0);
            acc[1][0] = __builtin_amdgcn_mfma_f32_16x16x32_bf16(a1, b0, acc[1][0], 0, 0, 0);
            acc[1][1] = __builtin_amdgcn_mfma_f32_16x16x32_bf16(a1, b1, acc[1][1], 0, 0, 0);
            acc[0][0] = __builtin_amdgcn_mfma_f32_16x16x32_bf16(a0, bl0, acc[0][0], 0, 0, 0);
            acc[0][1] = __builtin_amdgcn_mfma_f32_16x16x32_bf16(a0, bl1, acc[0][1], 0, 0, 0);
            acc[1][0] = __builtin_amdgcn_mfma_f32_16x16x32_bf16(a1, bl0, acc[1][0], 0, 0, 0);
            acc[1][1] = __builtin_amdgcn_mfma_f32_16x16x32_bf16(a1, bl1, acc[1][1], 0, 0, 0);
            acc[0][0] = __builtin_amdgcn_mfma_f32_16x16x32_bf16(al0, b0, acc[0][0], 0, 0, 0);
            acc[0][1] = __builtin_amdgcn_mfma_f32_16x16x32_bf16(al0, b1, acc[0][1], 0, 0, 0);
            acc[1][0] = __builtin_amdgcn_mfma_f32_16x16x32_bf16(al1, b0, acc[1][0], 0, 0, 0);
            acc[1][1] = __builtin_amdgcn_mfma_f32_16x16x32_bf16(al1, b1, acc[1][1], 0, 0, 0);
        }
    }

    float* __restrict__ Pz = P + (size_t)z * T_TOK * D;
    #pragma unroll
    for (int fm = 0; fm < 2; ++fm)
        #pragma unroll
        for (int fn = 0; fn < 2; ++fn)
            #pragma unroll
            for (int r = 0; r < 4; ++r) {
                int row = bm + wr * 32 + fm * 16 + mi[r];
                int col = bn + wc * 32 + fn * 16 + ni[r];
                Pz[(size_t)row * D + col] = acc[fm][fn][r];
            }
}

// ---------------------------------------------------------------------------
// Kernel 2: per-token epilogue via rank-1 layernorm collapse.
//   y[i] = w2[i]*S*rsqrt(w2[i]^2*var1+eps) + (wb[i]-mu_b)*rsqrt(var_b+eps)
//   S = <w1,x> - mean(w1)*sum(x)
// ---------------------------------------------------------------------------
__global__ __launch_bounds__(256) void epilogue_kernel(
    const float* __restrict__ X,
    const float* __restrict__ P,    // [3][T_TOK][D]
    float* __restrict__ Y)
{
    const int t   = blockIdx.x;
    const int tid = threadIdx.x;

    const float* __restrict__ w1 = P + (size_t)t * D;
    const float* __restrict__ w2 = P + (size_t)T_TOK * D     + (size_t)t * D;
    const float* __restrict__ wb = P + (size_t)T_TOK * D * 2 + (size_t)t * D;
    const float* __restrict__ x  = X + (size_t)t * D;

    float sx = 0.f, s1 = 0.f, q1 = 0.f, d1x = 0.f, sb = 0.f, qb = 0.f;
    #pragma unroll
    for (int i = tid; i < D; i += 256) {
        float xv  = x[i];
        float w1v = w1[i];
        float wbv = wb[i];
        sx  += xv;
        s1  += w1v;
        q1  += w1v * w1v;
        d1x += w1v * xv;
        sb  += wbv;
        qb  += wbv * wbv;
    }

    #pragma unroll
    for (int off = 32; off > 0; off >>= 1) {
        sx  += __shfl_down(sx,  off);
        s1  += __shfl_down(s1,  off);
        q1  += __shfl_down(q1,  off);
        d1x += __shfl_down(d1x, off);
        sb  += __shfl_down(sb,  off);
        qb  += __shfl_down(qb,  off);
    }

    __shared__ float red[6][4];
    const int wave = tid >> 6;
    if ((tid & 63) == 0) {
        red[0][wave] = sx;  red[1][wave] = s1;  red[2][wave] = q1;
        red[3][wave] = d1x; red[4][wave] = sb;  red[5][wave] = qb;
    }
    __syncthreads();
    sx  = red[0][0] + red[0][1] + red[0][2] + red[0][3];
    s1  = red[1][0] + red[1][1] + red[1][2] + red[1][3];
    q1  = red[2][0] + red[2][1] + red[2][2] + red[2][3];
    d1x = red[3][0] + red[3][1] + red[3][2] + red[3][3];
    sb  = red[4][0] + red[4][1] + red[4][2] + red[4][3];
    qb  = red[5][0] + red[5][1] + red[5][2] + red[5][3];

    const float inv_d = 1.f / (float)D;
    const float mu1   = s1 * inv_d;
    const float var1  = q1 * inv_d - mu1 * mu1;
    const float Sv    = d1x - mu1 * sx;
    const float mub   = sb * inv_d;
    const float varb  = qb * inv_d - mub * mub;
    const float rb    = rsqrtf(varb + EPS);

    #pragma unroll
    for (int i = tid; i < D; i += 256) {
        float w2v = w2[i];
        float wbv = wb[i];
        float y = w2v * Sv * rsqrtf(w2v * w2v * var1 + EPS)
                + (wbv - mub) * rb;
        Y[(size_t)t * D + i] = y;
    }
}

extern "C" void kernel_launch(void* const* d_in, const int* in_sizes, int n_in,
                              void* d_out, int out_size, void* d_ws, size_t ws_size,
                              hipStream_t stream) {
    const float* x     = (const float*)d_in[0];
    const float* W_in  = (const float*)d_in[1];
    const float* W_out = (const float*)d_in[2];
    const float* W_b   = (const float*)d_in[3];
    float* Y = (float*)d_out;

    char* ws = (char*)d_ws;
    float*          P   = (float*)(ws);                       // 6 MB
    unsigned short* Xh  = (unsigned short*)(ws + 6291456);    // 1 MB
    unsigned short* Xl  = (unsigned short*)(ws + 7340032);    // 1 MB
    unsigned short* Wh  = (unsigned short*)(ws + 8388608);    // 1.5 MB
    unsigned short* W1l = (unsigned short*)(ws + 9961472);    // 0.5 MB

    convert_kernel<<<dim3(1280), 256, 0, stream>>>(
        x, W_in, W_out, W_b, Xh, Xl, Wh, W1l);

    gemm_reg<<<dim3(T_TOK / 64, D / 64, 3), 256, 0, stream>>>(
        Xh, Xl, Wh, W1l, P);

    epilogue_kernel<<<dim3(T_TOK), 256, 0, stream>>>(x, P, Y);
}

// Round 6
// 31.973 us; speedup vs baseline: 1.4072x; 1.0898x over previous
//
#include <hip/hip_runtime.h>
#include <math.h>

#define T_TOK 1024   // B*S
#define D 512        // D_IN = D_OUT
#define EPS 1e-5f

typedef short bf16x8 __attribute__((ext_vector_type(8)));
typedef float f32x4  __attribute__((ext_vector_type(4)));

__device__ __forceinline__ unsigned short f2bf(float f) {
    unsigned int u = __builtin_bit_cast(unsigned int, f);
    u += 0x7FFFu + ((u >> 16) & 1u);   // RNE
    return (unsigned short)(u >> 16);
}
__device__ __forceinline__ float bf2f(unsigned short h) {
    return __builtin_bit_cast(float, (unsigned int)h << 16);
}

// workspace layout (bytes):
//   P    f32 [3][1024][512]  @ 0         (6 MB)
//   Xh   u16 [1024][512]     @ 6291456   (1 MB)
//   Xl   u16 [1024][512]     @ 7340032   (1 MB)
//   Wh   u16 [3][512][512]   @ 8388608   (1.5 MB)
//   W1l  u16 [512][512]      @ 9961472   (0.5 MB)

// ---------------------------------------------------------------------------
// Kernel 0: one-shot fp32 -> bf16 (hi everywhere; exact residual lo for X
// and W_out, needed by the split-precision w2 GEMM).
// ---------------------------------------------------------------------------
__global__ __launch_bounds__(256) void convert_kernel(
    const float* __restrict__ X,
    const float* __restrict__ W0,
    const float* __restrict__ W1,
    const float* __restrict__ W2,
    unsigned short* __restrict__ Xh,
    unsigned short* __restrict__ Xl,
    unsigned short* __restrict__ Wh,
    unsigned short* __restrict__ W1l)
{
    constexpr int NX4 = T_TOK * D / 4;   // 131072
    constexpr int NW4 = D * D / 4;       // 65536
    const int i = blockIdx.x * 256 + threadIdx.x;

    if (i < NX4) {
        float4 v = reinterpret_cast<const float4*>(X)[i];
        unsigned short h0 = f2bf(v.x), h1 = f2bf(v.y),
                       h2 = f2bf(v.z), h3 = f2bf(v.w);
        ushort4 h = {h0, h1, h2, h3};
        ushort4 l = {f2bf(v.x - bf2f(h0)), f2bf(v.y - bf2f(h1)),
                     f2bf(v.z - bf2f(h2)), f2bf(v.w - bf2f(h3))};
        reinterpret_cast<ushort4*>(Xh)[i] = h;
        reinterpret_cast<ushort4*>(Xl)[i] = l;
    } else {
        int w = i - NX4;                 // 0 .. 3*NW4-1
        int z = w / NW4;
        int j = w - z * NW4;
        const float* Wsrc = (z == 0) ? W0 : (z == 1) ? W1 : W2;
        float4 v = reinterpret_cast<const float4*>(Wsrc)[j];
        unsigned short h0 = f2bf(v.x), h1 = f2bf(v.y),
                       h2 = f2bf(v.z), h3 = f2bf(v.w);
        ushort4 h = {h0, h1, h2, h3};
        reinterpret_cast<ushort4*>(Wh)[w] = h;
        if (z == 1) {
            ushort4 l = {f2bf(v.x - bf2f(h0)), f2bf(v.y - bf2f(h1)),
                         f2bf(v.z - bf2f(h2)), f2bf(v.w - bf2f(h3))};
            reinterpret_cast<ushort4*>(W1l)[j] = l;
        }
    }
}

// ---------------------------------------------------------------------------
// Kernel 1: LDS-staged bf16 MFMA GEMM. P[z][t][e] = sum_d X[t][d]*Wz[e][d].
// 64x64 tile, BK=64, 4 waves (2x2), wave owns 32x32.
// Staging: coalesced 16B global loads of PRE-CONVERTED bf16 -> ds_write_b128
// into padded rows (LSTR=72 shorts = 144B: 16B-aligned, start banks rotate
// by 4 words/row -> only free 2-way aliasing on fragment reads).
// z==1 split precision as 3 SEQUENTIAL K-PASSES into the same accumulator
// (Ah*Bh + Ah*Bl + Al*Bh), so only 2 LDS buffers are needed.
// C-write self-calibrates via two probe MFMAs.
// ---------------------------------------------------------------------------
#define LSTR 72

__global__ __launch_bounds__(256) void gemm_lds(
    const unsigned short* __restrict__ Xh,
    const unsigned short* __restrict__ Xl,
    const unsigned short* __restrict__ Wh,
    const unsigned short* __restrict__ W1l,
    float* __restrict__ P)
{
    __shared__ __align__(16) unsigned short SA[64 * LSTR];
    __shared__ __align__(16) unsigned short SB[64 * LSTR];

    const int tid  = threadIdx.x;
    const int lane = tid & 63;
    const int wid  = tid >> 6;
    const int wr   = wid >> 1;
    const int wc   = wid & 1;
    const int bm   = blockIdx.x * 64;
    const int bn   = blockIdx.y * 64;
    const int z    = blockIdx.z;
    const int l15  = lane & 15;
    const int l4   = lane >> 4;

    // --- layout probes: D1[m][n]=m, D2[m][n]=n under the load convention ---
    bf16x8 aP1 = {}, bP1 = {}, aP2 = {}, bP2 = {};
    if (l4 == 0) {
        aP1[0] = (short)f2bf((float)l15);
        bP1[0] = (short)f2bf(1.0f);
        aP2[0] = (short)f2bf(1.0f);
        bP2[0] = (short)f2bf((float)l15);
    }
    f32x4 zero = {};
    f32x4 D1 = __builtin_amdgcn_mfma_f32_16x16x32_bf16(aP1, bP1, zero, 0, 0, 0);
    f32x4 D2 = __builtin_amdgcn_mfma_f32_16x16x32_bf16(aP2, bP2, zero, 0, 0, 0);
    int mi[4], ni[4];
    #pragma unroll
    for (int r = 0; r < 4; ++r) { mi[r] = (int)D1[r]; ni[r] = (int)D2[r]; }

    // staging coords: thread f covers (row = f>>3, 8 shorts at col (f&7)*8)
    const int srow = tid >> 3;
    const int scol = (tid & 7) * 8;

    f32x4 acc[2][2] = {};

    const int npass = (z == 1) ? 3 : 1;
    for (int p = 0; p < npass; ++p) {
        const unsigned short* __restrict__ Asrc = (p == 2) ? Xl : Xh;
        const unsigned short* __restrict__ Bsrc =
            (p == 1) ? W1l : (Wh + (size_t)z * D * D);

        for (int k0 = 0; k0 < D; k0 += 64) {
            // --- stage 64x64 bf16 tiles, coalesced 16B per thread x2 ---
            #pragma unroll
            for (int i = 0; i < 2; ++i) {
                int row = srow + i * 32;
                bf16x8 va = *reinterpret_cast<const bf16x8*>(
                    Asrc + (size_t)(bm + row) * D + k0 + scol);
                *reinterpret_cast<bf16x8*>(&SA[row * LSTR + scol]) = va;
                bf16x8 vb = *reinterpret_cast<const bf16x8*>(
                    Bsrc + (size_t)(bn + row) * D + k0 + scol);
                *reinterpret_cast<bf16x8*>(&SB[row * LSTR + scol]) = vb;
            }
            __syncthreads();

            #pragma unroll
            for (int kc = 0; kc < 2; ++kc) {
                const int ko = kc * 32 + l4 * 8;
                bf16x8 a0 = *reinterpret_cast<const bf16x8*>(
                    &SA[(wr * 32 + l15) * LSTR + ko]);
                bf16x8 a1 = *reinterpret_cast<const bf16x8*>(
                    &SA[(wr * 32 + 16 + l15) * LSTR + ko]);
                bf16x8 b0 = *reinterpret_cast<const bf16x8*>(
                    &SB[(wc * 32 + l15) * LSTR + ko]);
                bf16x8 b1 = *reinterpret_cast<const bf16x8*>(
                    &SB[(wc * 32 + 16 + l15) * LSTR + ko]);
                acc[0][0] = __builtin_amdgcn_mfma_f32_16x16x32_bf16(a0, b0, acc[0][0], 0, 0, 0);
                acc[0][1] = __builtin_amdgcn_mfma_f32_16x16x32_bf16(a0, b1, acc[0][1], 0, 0, 0);
                acc[1][0] = __builtin_amdgcn_mfma_f32_16x16x32_bf16(a1, b0, acc[1][0], 0, 0, 0);
                acc[1][1] = __builtin_amdgcn_mfma_f32_16x16x32_bf16(a1, b1, acc[1][1], 0, 0, 0);
            }
            __syncthreads();
        }
    }

    float* __restrict__ Pz = P + (size_t)z * T_TOK * D;
    #pragma unroll
    for (int fm = 0; fm < 2; ++fm)
        #pragma unroll
        for (int fn = 0; fn < 2; ++fn)
            #pragma unroll
            for (int r = 0; r < 4; ++r) {
                int row = bm + wr * 32 + fm * 16 + mi[r];
                int col = bn + wc * 32 + fn * 16 + ni[r];
                Pz[(size_t)row * D + col] = acc[fm][fn][r];
            }
}

// ---------------------------------------------------------------------------
// Kernel 2: per-token epilogue via rank-1 layernorm collapse (float2 loads).
//   y[i] = w2[i]*S*rsqrt(w2[i]^2*var1+eps) + (wb[i]-mu_b)*rsqrt(var_b+eps)
// ---------------------------------------------------------------------------
__global__ __launch_bounds__(256) void epilogue_kernel(
    const float* __restrict__ X,
    const float* __restrict__ P,    // [3][T_TOK][D]
    float* __restrict__ Y)
{
    const int t   = blockIdx.x;
    const int tid = threadIdx.x;

    const float2* __restrict__ w1 = (const float2*)(P + (size_t)t * D);
    const float2* __restrict__ w2 = (const float2*)(P + (size_t)T_TOK * D + (size_t)t * D);
    const float2* __restrict__ wb = (const float2*)(P + (size_t)T_TOK * D * 2 + (size_t)t * D);
    const float2* __restrict__ x  = (const float2*)(X + (size_t)t * D);

    float2 xv  = x[tid];
    float2 w1v = w1[tid];
    float2 wbv = wb[tid];

    float sx  = xv.x + xv.y;
    float s1  = w1v.x + w1v.y;
    float q1  = w1v.x * w1v.x + w1v.y * w1v.y;
    float d1x = w1v.x * xv.x + w1v.y * xv.y;
    float sb  = wbv.x + wbv.y;
    float qb  = wbv.x * wbv.x + wbv.y * wbv.y;

    #pragma unroll
    for (int off = 32; off > 0; off >>= 1) {
        sx  += __shfl_down(sx,  off);
        s1  += __shfl_down(s1,  off);
        q1  += __shfl_down(q1,  off);
        d1x += __shfl_down(d1x, off);
        sb  += __shfl_down(sb,  off);
        qb  += __shfl_down(qb,  off);
    }

    __shared__ float red[6][4];
    const int wave = tid >> 6;
    if ((tid & 63) == 0) {
        red[0][wave] = sx;  red[1][wave] = s1;  red[2][wave] = q1;
        red[3][wave] = d1x; red[4][wave] = sb;  red[5][wave] = qb;
    }
    __syncthreads();
    sx  = red[0][0] + red[0][1] + red[0][2] + red[0][3];
    s1  = red[1][0] + red[1][1] + red[1][2] + red[1][3];
    q1  = red[2][0] + red[2][1] + red[2][2] + red[2][3];
    d1x = red[3][0] + red[3][1] + red[3][2] + red[3][3];
    sb  = red[4][0] + red[4][1] + red[4][2] + red[4][3];
    qb  = red[5][0] + red[5][1] + red[5][2] + red[5][3];

    const float inv_d = 1.f / (float)D;
    const float mu1   = s1 * inv_d;
    const float var1  = q1 * inv_d - mu1 * mu1;
    const float Sv    = d1x - mu1 * sx;
    const float mub   = sb * inv_d;
    const float varb  = qb * inv_d - mub * mub;
    const float rb    = rsqrtf(varb + EPS);

    float2 w2v = w2[tid];
    float2 y;
    y.x = w2v.x * Sv * rsqrtf(w2v.x * w2v.x * var1 + EPS) + (wbv.x - mub) * rb;
    y.y = w2v.y * Sv * rsqrtf(w2v.y * w2v.y * var1 + EPS) + (wbv.y - mub) * rb;
    reinterpret_cast<float2*>(Y + (size_t)t * D)[tid] = y;
}

extern "C" void kernel_launch(void* const* d_in, const int* in_sizes, int n_in,
                              void* d_out, int out_size, void* d_ws, size_t ws_size,
                              hipStream_t stream) {
    const float* x     = (const float*)d_in[0];
    const float* W_in  = (const float*)d_in[1];
    const float* W_out = (const float*)d_in[2];
    const float* W_b   = (const float*)d_in[3];
    float* Y = (float*)d_out;

    char* ws = (char*)d_ws;
    float*          P   = (float*)(ws);                       // 6 MB
    unsigned short* Xh  = (unsigned short*)(ws + 6291456);    // 1 MB
    unsigned short* Xl  = (unsigned short*)(ws + 7340032);    // 1 MB
    unsigned short* Wh  = (unsigned short*)(ws + 8388608);    // 1.5 MB
    unsigned short* W1l = (unsigned short*)(ws + 9961472);    // 0.5 MB

    convert_kernel<<<dim3(1280), 256, 0, stream>>>(
        x, W_in, W_out, W_b, Xh, Xl, Wh, W1l);

    gemm_lds<<<dim3(T_TOK / 64, D / 64, 3), 256, 0, stream>>>(
        Xh, Xl, Wh, W1l, P);

    epilogue_kernel<<<dim3(T_TOK), 256, 0, stream>>>(x, P, Y);
}

// Round 7
// 24.374 us; speedup vs baseline: 1.8459x; 1.3117x over previous
//
#include <hip/hip_runtime.h>
#include <math.h>

#define T_TOK 1024   // B*S
#define D 512        // D_IN = D_OUT
#define EPS 1e-5f

typedef short bf16x8 __attribute__((ext_vector_type(8)));
typedef float f32x4  __attribute__((ext_vector_type(4)));

__device__ __forceinline__ unsigned short f2bf(float f) {
    unsigned int u = __builtin_bit_cast(unsigned int, f);
    u += 0x7FFFu + ((u >> 16) & 1u);   // RNE
    return (unsigned short)(u >> 16);
}
__device__ __forceinline__ float bf2f(unsigned short h) {
    return __builtin_bit_cast(float, (unsigned int)h << 16);
}

// workspace layout (bytes):
//   P    f32 [5][1024][512]  @ 0          (10 MB)  slices: w1, w2hh, wb, w2hl, w2lh
//   Xh   u16 [1024][512]     @ 10485760   (1 MB)
//   Xl   u16 [1024][512]     @ 11534336   (1 MB)
//   Wh   u16 [3][512][512]   @ 12582912   (1.5 MB)
//   W1l  u16 [512][512]      @ 14155776   (0.5 MB)

// ---------------------------------------------------------------------------
// Kernel 0: one-shot fp32 -> bf16 (hi everywhere; exact residual lo for X
// and W_out, needed by the split-precision w2 GEMM).
// ---------------------------------------------------------------------------
__global__ __launch_bounds__(256) void convert_kernel(
    const float* __restrict__ X,
    const float* __restrict__ W0,
    const float* __restrict__ W1,
    const float* __restrict__ W2,
    unsigned short* __restrict__ Xh,
    unsigned short* __restrict__ Xl,
    unsigned short* __restrict__ Wh,
    unsigned short* __restrict__ W1l)
{
    constexpr int NX4 = T_TOK * D / 4;   // 131072
    constexpr int NW4 = D * D / 4;       // 65536
    const int i = blockIdx.x * 256 + threadIdx.x;

    if (i < NX4) {
        float4 v = reinterpret_cast<const float4*>(X)[i];
        unsigned short h0 = f2bf(v.x), h1 = f2bf(v.y),
                       h2 = f2bf(v.z), h3 = f2bf(v.w);
        ushort4 h = {h0, h1, h2, h3};
        ushort4 l = {f2bf(v.x - bf2f(h0)), f2bf(v.y - bf2f(h1)),
                     f2bf(v.z - bf2f(h2)), f2bf(v.w - bf2f(h3))};
        reinterpret_cast<ushort4*>(Xh)[i] = h;
        reinterpret_cast<ushort4*>(Xl)[i] = l;
    } else {
        int w = i - NX4;                 // 0 .. 3*NW4-1
        int z = w / NW4;
        int j = w - z * NW4;
        const float* Wsrc = (z == 0) ? W0 : (z == 1) ? W1 : W2;
        float4 v = reinterpret_cast<const float4*>(Wsrc)[j];
        unsigned short h0 = f2bf(v.x), h1 = f2bf(v.y),
                       h2 = f2bf(v.z), h3 = f2bf(v.w);
        ushort4 h = {h0, h1, h2, h3};
        reinterpret_cast<ushort4*>(Wh)[w] = h;
        if (z == 1) {
            ushort4 l = {f2bf(v.x - bf2f(h0)), f2bf(v.y - bf2f(h1)),
                         f2bf(v.z - bf2f(h2)), f2bf(v.w - bf2f(h3))};
            reinterpret_cast<ushort4*>(W1l)[j] = l;
        }
    }
}

// ---------------------------------------------------------------------------
// Kernel 1: balanced 5-slice bf16 MFMA GEMM, double-buffered LDS.
//   z=0: Xh*W0h -> P0 (w1)     z=1: Xh*W1h -> P1
//   z=2: Xh*W2h -> P2 (wb)     z=3: Xh*W1l -> P3    z=4: Xl*W1h -> P4
// Every block: exactly 8 k-steps, 2-phase pipeline (prefetch regs while
// MFMA consumes current LDS buffer; one barrier per step).
// C-write self-calibrates via two probe MFMAs.
// ---------------------------------------------------------------------------
#define LSTR 72

__global__ __launch_bounds__(256) void gemm_bal(
    const unsigned short* __restrict__ Xh,
    const unsigned short* __restrict__ Xl,
    const unsigned short* __restrict__ Wh,
    const unsigned short* __restrict__ W1l,
    float* __restrict__ P)
{
    __shared__ __align__(16) unsigned short SA[2][64 * LSTR];
    __shared__ __align__(16) unsigned short SB[2][64 * LSTR];

    const int tid  = threadIdx.x;
    const int lane = tid & 63;
    const int wid  = tid >> 6;
    const int wr   = wid >> 1;
    const int wc   = wid & 1;
    const int bm   = blockIdx.x * 64;
    const int bn   = blockIdx.y * 64;
    const int z    = blockIdx.z;
    const int l15  = lane & 15;
    const int l4   = lane >> 4;

    const unsigned short* __restrict__ A = (z == 4) ? Xl : Xh;
    const unsigned short* __restrict__ B =
        (z == 3) ? W1l : Wh + (size_t)(z == 4 ? 1 : z) * D * D;

    // --- layout probes: D1[m][n]=m, D2[m][n]=n under the load convention ---
    bf16x8 aP1 = {}, bP1 = {}, aP2 = {}, bP2 = {};
    if (l4 == 0) {
        aP1[0] = (short)f2bf((float)l15);
        bP1[0] = (short)f2bf(1.0f);
        aP2[0] = (short)f2bf(1.0f);
        bP2[0] = (short)f2bf((float)l15);
    }
    f32x4 zero = {};
    f32x4 D1 = __builtin_amdgcn_mfma_f32_16x16x32_bf16(aP1, bP1, zero, 0, 0, 0);
    f32x4 D2 = __builtin_amdgcn_mfma_f32_16x16x32_bf16(aP2, bP2, zero, 0, 0, 0);
    int mi[4], ni[4];
    #pragma unroll
    for (int r = 0; r < 4; ++r) { mi[r] = (int)D1[r]; ni[r] = (int)D2[r]; }

    // staging coords: thread covers rows {srow, srow+32}, 8 shorts at scol
    const int srow = tid >> 3;
    const int scol = (tid & 7) * 8;
    const size_t ga0 = (size_t)(bm + srow) * D + scol;
    const size_t ga1 = (size_t)(bm + srow + 32) * D + scol;
    const size_t gb0 = (size_t)(bn + srow) * D + scol;
    const size_t gb1 = (size_t)(bn + srow + 32) * D + scol;

    f32x4 acc[2][2] = {};
    bf16x8 va0, va1, vb0, vb1;

    // prologue: tile 0 -> regs -> LDS[0]
    va0 = *reinterpret_cast<const bf16x8*>(A + ga0);
    va1 = *reinterpret_cast<const bf16x8*>(A + ga1);
    vb0 = *reinterpret_cast<const bf16x8*>(B + gb0);
    vb1 = *reinterpret_cast<const bf16x8*>(B + gb1);
    *reinterpret_cast<bf16x8*>(&SA[0][srow * LSTR + scol])        = va0;
    *reinterpret_cast<bf16x8*>(&SA[0][(srow + 32) * LSTR + scol]) = va1;
    *reinterpret_cast<bf16x8*>(&SB[0][srow * LSTR + scol])        = vb0;
    *reinterpret_cast<bf16x8*>(&SB[0][(srow + 32) * LSTR + scol]) = vb1;
    __syncthreads();

    int cur = 0;
    #pragma unroll
    for (int t = 0; t < 8; ++t) {
        if (t < 7) {
            const int k0 = (t + 1) * 64;
            va0 = *reinterpret_cast<const bf16x8*>(A + ga0 + k0);
            va1 = *reinterpret_cast<const bf16x8*>(A + ga1 + k0);
            vb0 = *reinterpret_cast<const bf16x8*>(B + gb0 + k0);
            vb1 = *reinterpret_cast<const bf16x8*>(B + gb1 + k0);
        }

        #pragma unroll
        for (int kc = 0; kc < 2; ++kc) {
            const int ko = kc * 32 + l4 * 8;
            bf16x8 a0 = *reinterpret_cast<const bf16x8*>(
                &SA[cur][(wr * 32 + l15) * LSTR + ko]);
            bf16x8 a1 = *reinterpret_cast<const bf16x8*>(
                &SA[cur][(wr * 32 + 16 + l15) * LSTR + ko]);
            bf16x8 b0 = *reinterpret_cast<const bf16x8*>(
                &SB[cur][(wc * 32 + l15) * LSTR + ko]);
            bf16x8 b1 = *reinterpret_cast<const bf16x8*>(
                &SB[cur][(wc * 32 + 16 + l15) * LSTR + ko]);
            acc[0][0] = __builtin_amdgcn_mfma_f32_16x16x32_bf16(a0, b0, acc[0][0], 0, 0, 0);
            acc[0][1] = __builtin_amdgcn_mfma_f32_16x16x32_bf16(a0, b1, acc[0][1], 0, 0, 0);
            acc[1][0] = __builtin_amdgcn_mfma_f32_16x16x32_bf16(a1, b0, acc[1][0], 0, 0, 0);
            acc[1][1] = __builtin_amdgcn_mfma_f32_16x16x32_bf16(a1, b1, acc[1][1], 0, 0, 0);
        }

        if (t < 7) {
            const int nxt = cur ^ 1;
            *reinterpret_cast<bf16x8*>(&SA[nxt][srow * LSTR + scol])        = va0;
            *reinterpret_cast<bf16x8*>(&SA[nxt][(srow + 32) * LSTR + scol]) = va1;
            *reinterpret_cast<bf16x8*>(&SB[nxt][srow * LSTR + scol])        = vb0;
            *reinterpret_cast<bf16x8*>(&SB[nxt][(srow + 32) * LSTR + scol]) = vb1;
            __syncthreads();
            cur = nxt;
        }
    }

    float* __restrict__ Pz = P + (size_t)z * T_TOK * D;
    #pragma unroll
    for (int fm = 0; fm < 2; ++fm)
        #pragma unroll
        for (int fn = 0; fn < 2; ++fn)
            #pragma unroll
            for (int r = 0; r < 4; ++r) {
                int row = bm + wr * 32 + fm * 16 + mi[r];
                int col = bn + wc * 32 + fn * 16 + ni[r];
                Pz[(size_t)row * D + col] = acc[fm][fn][r];
            }
}

// ---------------------------------------------------------------------------
// Kernel 2: per-token epilogue via rank-1 layernorm collapse.
//   w1 = P0, wb = P2, w2 = P1 + P3 + P4
//   y[i] = w2[i]*S*rsqrt(w2[i]^2*var1+eps) + (wb[i]-mu_b)*rsqrt(var_b+eps)
// ---------------------------------------------------------------------------
__global__ __launch_bounds__(256) void epilogue_kernel(
    const float* __restrict__ X,
    const float* __restrict__ P,    // [5][T_TOK][D]
    float* __restrict__ Y)
{
    const int t   = blockIdx.x;
    const int tid = threadIdx.x;
    constexpr size_t SL = (size_t)T_TOK * D;

    const float2* __restrict__ w1 = (const float2*)(P            + (size_t)t * D);
    const float2* __restrict__ p1 = (const float2*)(P + SL       + (size_t)t * D);
    const float2* __restrict__ wb = (const float2*)(P + SL * 2   + (size_t)t * D);
    const float2* __restrict__ p3 = (const float2*)(P + SL * 3   + (size_t)t * D);
    const float2* __restrict__ p4 = (const float2*)(P + SL * 4   + (size_t)t * D);
    const float2* __restrict__ x  = (const float2*)(X            + (size_t)t * D);

    float2 xv  = x[tid];
    float2 w1v = w1[tid];
    float2 wbv = wb[tid];

    float sx  = xv.x + xv.y;
    float s1  = w1v.x + w1v.y;
    float q1  = w1v.x * w1v.x + w1v.y * w1v.y;
    float d1x = w1v.x * xv.x + w1v.y * xv.y;
    float sb  = wbv.x + wbv.y;
    float qb  = wbv.x * wbv.x + wbv.y * wbv.y;

    #pragma unroll
    for (int off = 32; off > 0; off >>= 1) {
        sx  += __shfl_down(sx,  off);
        s1  += __shfl_down(s1,  off);
        q1  += __shfl_down(q1,  off);
        d1x += __shfl_down(d1x, off);
        sb  += __shfl_down(sb,  off);
        qb  += __shfl_down(qb,  off);
    }

    __shared__ float red[6][4];
    const int wave = tid >> 6;
    if ((tid & 63) == 0) {
        red[0][wave] = sx;  red[1][wave] = s1;  red[2][wave] = q1;
        red[3][wave] = d1x; red[4][wave] = sb;  red[5][wave] = qb;
    }
    __syncthreads();
    sx  = red[0][0] + red[0][1] + red[0][2] + red[0][3];
    s1  = red[1][0] + red[1][1] + red[1][2] + red[1][3];
    q1  = red[2][0] + red[2][1] + red[2][2] + red[2][3];
    d1x = red[3][0] + red[3][1] + red[3][2] + red[3][3];
    sb  = red[4][0] + red[4][1] + red[4][2] + red[4][3];
    qb  = red[5][0] + red[5][1] + red[5][2] + red[5][3];

    const float inv_d = 1.f / (float)D;
    const float mu1   = s1 * inv_d;
    const float var1  = q1 * inv_d - mu1 * mu1;
    const float Sv    = d1x - mu1 * sx;
    const float mub   = sb * inv_d;
    const float varb  = qb * inv_d - mub * mub;
    const float rb    = rsqrtf(varb + EPS);

    float2 a = p1[tid], b = p3[tid], c = p4[tid];
    float2 w2v = {a.x + b.x + c.x, a.y + b.y + c.y};
    float2 y;
    y.x = w2v.x * Sv * rsqrtf(w2v.x * w2v.x * var1 + EPS) + (wbv.x - mub) * rb;
    y.y = w2v.y * Sv * rsqrtf(w2v.y * w2v.y * var1 + EPS) + (wbv.y - mub) * rb;
    reinterpret_cast<float2*>(Y + (size_t)t * D)[tid] = y;
}

extern "C" void kernel_launch(void* const* d_in, const int* in_sizes, int n_in,
                              void* d_out, int out_size, void* d_ws, size_t ws_size,
                              hipStream_t stream) {
    const float* x     = (const float*)d_in[0];
    const float* W_in  = (const float*)d_in[1];
    const float* W_out = (const float*)d_in[2];
    const float* W_b   = (const float*)d_in[3];
    float* Y = (float*)d_out;

    char* ws = (char*)d_ws;
    float*          P   = (float*)(ws);                        // 10 MB
    unsigned short* Xh  = (unsigned short*)(ws + 10485760);    // 1 MB
    unsigned short* Xl  = (unsigned short*)(ws + 11534336);    // 1 MB
    unsigned short* Wh  = (unsigned short*)(ws + 12582912);    // 1.5 MB
    unsigned short* W1l = (unsigned short*)(ws + 14155776);    // 0.5 MB

    convert_kernel<<<dim3(1280), 256, 0, stream>>>(
        x, W_in, W_out, W_b, Xh, Xl, Wh, W1l);

    gemm_bal<<<dim3(T_TOK / 64, D / 64, 5), 256, 0, stream>>>(
        Xh, Xl, Wh, W1l, P);

    epilogue_kernel<<<dim3(T_TOK), 256, 0, stream>>>(x, P, Y);
}